// Round 10
// baseline (159.630 us; speedup 1.0000x reference)
//
#include <hip/hip_runtime.h>
#include <math.h>

// AutoregressiveFlowLayer MI355X — round 10.
// R9 post-mortem (WIN, matched): 70us; LDS ~45us busy, VALU ~24, MFMA ~17 =>
// ~25us barrier serialization left (2 barriers x 16 tiles). Traffic is structurally
// minimal (4-wave col-partition forced by register budget). So: 1 barrier/tile.
// R10: parity-pipelined single barrier, 2 blocks/CU:
//   I(t) = store(t-2) | gather(t+2)->xg[t&1] | P2(t):h1[t&1]->h2[t&1]
//        | P3(t-1)+epi(t-1):h2[(t-1)&1] | P1(t+1):xg[(t+1)&1]->h1[(t+1)&1]
// Hazards (producer -> consumer, adjacent intervals, barrier-separated):
//   h1[b]: P1(t+1)@I(t) -> P2(t+1)@I(t+1); next write P1(t+3)@I(t+2).
//   h2[b]: P2(t)@I(t) -> P3(t)@I(t+1); next write P2(t+2)@I(t+2).
//   xg[b]: gather(t+2)@I(t) -> P1(t+2)@I(t+1); prior reader P1(t)@I(t-1).
//   red[b]: epi(t-1)@I(t) -> store(t-1)@I(t+1); next write epi(t+1)@I(t+2).
//   Concurrent stages in one interval touch OPPOSITE parities (checked above).
// Fit 2 blocks/CU (<=80KB) with doubled h buffers:
//   (a) XOR-swizzle, zero-pad: h stride 128 u16, swizzle col^(16*(row&7));
//       xg stride 32 u16, swizzle col^(8*(row&3)). Verified: b128 reads 8 dw/bank
//       (min), ushort4 stores 4 dw/bank (min). Swizzle algebra: k0 8-aligned,
//       s mult of 8/16 => ((k0^s)+j)^s = k0+j for j<8 (frag order preserved).
//   (b) xgf deleted; epilogue x re-loaded direct from global (4 L2-warm dwords/
//       thread/tile; HBM at 8% has headroom).  LDS = 73.3 KB.
// Kept: operand swap (weights=A, R9), weights via LDS scratch->reg frags (R4:
// direct global->reg spills), hi/lo planes + trunc lo (R7), >=2 waves/SIMD (R8).

#define RR 32
#define DD 1024
#define HH 128
#define OO 64
#define TROWS 32
#define TILES 16
#define BPR 16

#define SH  128   // u16 stride, h planes (swizzled, zero pad)
#define SX  32    // u16 stride, xg planes (swizzled, zero pad)
#define SSC 132   // u32 scratch stride (preamble weight staging)

typedef short bf16x8_t __attribute__((ext_vector_type(8)));
typedef float f32x4_t __attribute__((ext_vector_type(4)));
typedef unsigned short u16;
typedef unsigned int u32;

__device__ __forceinline__ u16 bf16_rne(float x) {
    u32 u = __float_as_uint(x);
    u += 0x7FFFu + ((u >> 16) & 1u);
    return (u16)(u >> 16);
}
__device__ __forceinline__ float bf16_tof(u16 h) {
    return __uint_as_float(((u32)h) << 16);
}
__device__ __forceinline__ u16 lo_trunc(float v, u16 h) {
    return (u16)(__float_as_uint(v - bf16_tof(h)) >> 16);
}
__device__ __forceinline__ u32 pack_split(float v) {
    u16 h = bf16_rne(v);
    return (u32)h | ((u32)lo_trunc(v, h) << 16);
}
// preamble only
__device__ __forceinline__ void unpack8(const u32* p, bf16x8_t& hi, bf16x8_t& lo) {
    uint4 a = *reinterpret_cast<const uint4*>(p);
    uint4 b = *reinterpret_cast<const uint4*>(p + 4);
    union { u32 u[4]; bf16x8_t v; } H, L;
    H.u[0] = __builtin_amdgcn_perm(a.y, a.x, 0x05040100u);
    H.u[1] = __builtin_amdgcn_perm(a.w, a.z, 0x05040100u);
    H.u[2] = __builtin_amdgcn_perm(b.y, b.x, 0x05040100u);
    H.u[3] = __builtin_amdgcn_perm(b.w, b.z, 0x05040100u);
    L.u[0] = __builtin_amdgcn_perm(a.y, a.x, 0x07060302u);
    L.u[1] = __builtin_amdgcn_perm(a.w, a.z, 0x07060302u);
    L.u[2] = __builtin_amdgcn_perm(b.y, b.x, 0x07060302u);
    L.u[3] = __builtin_amdgcn_perm(b.w, b.z, 0x07060302u);
    hi = H.v; lo = L.v;
}
__device__ __forceinline__ f32x4_t mfma16(bf16x8_t a, bf16x8_t b, f32x4_t c) {
    return __builtin_amdgcn_mfma_f32_16x16x32_bf16(a, b, c, 0, 0, 0);
}
// swizzled addressing
__device__ __forceinline__ int hsw(int row, int col) {
    return row * SH + (col ^ (16 * (row & 7)));
}
__device__ __forceinline__ int xsw(int row, int col) {
    return row * SX + (col ^ (8 * (row & 3)));
}

// preamble: stage [K x 32] weight slice -> packed-dword [col][k] scratch
__device__ __forceinline__ void stage_block(const float* __restrict__ W,
                                            const int* __restrict__ M,
                                            int ldc, int c0, int K, u32* dst, int sd,
                                            int tid)
{
    const int kb = tid >> 3;
    const int cb = tid & 7;
    if (kb * 4 >= K) return;
    const int k0 = kb * 4;
    float e[4][4];
#pragma unroll
    for (int i = 0; i < 4; ++i) {
        const int o = ((k0 + i) * ldc + c0 + 4 * cb) >> 2;
        float4 w = ((const float4*)W)[o];
        int4   m = ((const int4*)M)[o];
        e[i][0] = m.x ? w.x : 0.f; e[i][1] = m.y ? w.y : 0.f;
        e[i][2] = m.z ? w.z : 0.f; e[i][3] = m.w ? w.w : 0.f;
    }
#pragma unroll
    for (int j = 0; j < 4; ++j) {
        uint4 p;
        p.x = pack_split(e[0][j]); p.y = pack_split(e[1][j]);
        p.z = pack_split(e[2][j]); p.w = pack_split(e[3][j]);
        *(uint4*)&dst[(4 * cb + j) * sd + k0] = p;
    }
}

__global__ __launch_bounds__(256, 2)
void made_flow_r10(const float* __restrict__ inputs,
                   const float* __restrict__ W1,
                   const float* __restrict__ W2,
                   const float* __restrict__ Wout,
                   const int* __restrict__ idx,
                   const int* __restrict__ valid,
                   const int* __restrict__ M1,
                   const int* __restrict__ M2,
                   const int* __restrict__ Mout,
                   float* __restrict__ out)
{
    // [buf][plane][row*SH] ; h1 buf0 also hosts preamble scratch (16896B <= 16384B*2)
    __shared__ __align__(16) u16 h1p[2][2][TROWS * SH];   // 32 KB
    __shared__ __align__(16) u16 h2p[2][2][TROWS * SH];   // 32 KB
    __shared__ __align__(16) u16 xgp[2][2][TROWS * SX];   // 8 KB
    __shared__ __align__(16) float red[2][TROWS][4];      // 1 KB
    __shared__ int   idx_s[RR];
    __shared__ float v_s[RR];

    u32* const scr = (u32*)&h1p[0][0][0];   // preamble scratch (spans h1[0] planes)

    const int tid  = threadIdx.x;
    const int r    = blockIdx.x / BPR;
    const int rb   = blockIdx.x % BPR;
    const int lane = tid & 63;
    const int wave = tid >> 6;
    const int q    = lane >> 4;
    const int l16  = lane & 15;

    if (tid < RR) {
        idx_s[tid] = idx[r * RR + tid];
        v_s[tid]   = valid[r * RR + tid] ? 1.f : 0.f;
    }

    // ---- stage all weights -> per-wave register A-frags (W^T) via LDS scratch ----
    bf16x8_t a1h[2], a1l[2];        // W1^T cols 32w+16mi+l16
    bf16x8_t a2h[2][4], a2l[2][4];  // W2^T [mi][ks]
    bf16x8_t aoh[4],    aol[4];     // Wout^T cols 16w+l16
    {
        const float* W1r = W1 + r * RR * HH;   const int* M1r = M1 + r * RR * HH;
        const float* W2r = W2 + r * HH * HH;   const int* M2r = M2 + r * HH * HH;
        const float* Wor = Wout + r * HH * OO; const int* Mor = Mout + r * HH * OO;
        for (int c = 0; c < 4; ++c) {
            __syncthreads();
            stage_block(W2r, M2r, HH, 32 * c, HH, scr, SSC, tid);
            __syncthreads();
            if (wave == c) {
#pragma unroll
                for (int mi = 0; mi < 2; ++mi)
#pragma unroll
                    for (int ks = 0; ks < 4; ++ks)
                        unpack8(&scr[(16 * mi + l16) * SSC + ks * 32 + q * 8],
                                a2h[mi][ks], a2l[mi][ks]);
            }
        }
        for (int c = 0; c < 2; ++c) {
            __syncthreads();
            stage_block(Wor, Mor, OO, 32 * c, HH, scr, SSC, tid);
            __syncthreads();
            if ((wave >> 1) == c) {
                const int nl = wave & 1;
#pragma unroll
                for (int ks = 0; ks < 4; ++ks)
                    unpack8(&scr[(16 * nl + l16) * SSC + ks * 32 + q * 8],
                            aoh[ks], aol[ks]);
            }
        }
        for (int c = 0; c < 4; ++c) {
            __syncthreads();
            stage_block(W1r, M1r, HH, 32 * c, RR, scr, SSC, tid);  // K=32
            __syncthreads();
            if (wave == c) {
#pragma unroll
                for (int mi = 0; mi < 2; ++mi)
                    unpack8(&scr[(16 * mi + l16) * SSC + q * 8], a1h[mi], a1l[mi]);
            }
        }
    }

    const f32x4_t zero4 = {0.f, 0.f, 0.f, 0.f};
    const int grow = tid >> 3, gg = tid & 7;
    const int row0g = rb * TILES * TROWS;

    // ---- prologue: gather(0)->xg[0], gather(1)->xg[1] (xgp disjoint from scr) ----
#pragma unroll
    for (int tt = 0; tt < 2; ++tt) {
        const int base = (row0g + tt * TROWS + grow) * DD;
        float gx[4];
#pragma unroll
        for (int u = 0; u < 4; ++u)
            gx[u] = inputs[base + idx_s[4 * gg + u]] * v_s[4 * gg + u];
        ushort4 gh, gl;
        gh.x = bf16_rne(gx[0]); gl.x = lo_trunc(gx[0], gh.x);
        gh.y = bf16_rne(gx[1]); gl.y = lo_trunc(gx[1], gh.y);
        gh.z = bf16_rne(gx[2]); gl.z = lo_trunc(gx[2], gh.z);
        gh.w = bf16_rne(gx[3]); gl.w = lo_trunc(gx[3], gh.w);
        const int o = xsw(grow, 4 * gg);
        *(ushort4*)&xgp[tt][0][o] = gh;
        *(ushort4*)&xgp[tt][1][o] = gl;
    }
    __syncthreads();   // scr unpack-reads done before h1 writes; xg visible

    // ---- prologue: P1(0) -> h1[0] ----
    {
        bf16x8_t bh[2], bl[2];
#pragma unroll
        for (int ni = 0; ni < 2; ++ni) {
            const int o = xsw(16 * ni + l16, q * 8);
            bh[ni] = *(const bf16x8_t*)&xgp[0][0][o];
            bl[ni] = *(const bf16x8_t*)&xgp[0][1][o];
        }
#pragma unroll
        for (int mi = 0; mi < 2; ++mi)
#pragma unroll
            for (int ni = 0; ni < 2; ++ni) {
                f32x4_t a = zero4;
                a = mfma16(a1h[mi], bh[ni], a);
                a = mfma16(a1l[mi], bh[ni], a);
                a = mfma16(a1h[mi], bl[ni], a);
                ushort4 vh, vl;
                float v0 = fmaxf(a[0], 0.f), v1 = fmaxf(a[1], 0.f);
                float v2 = fmaxf(a[2], 0.f), v3 = fmaxf(a[3], 0.f);
                vh.x = bf16_rne(v0); vl.x = lo_trunc(v0, vh.x);
                vh.y = bf16_rne(v1); vl.y = lo_trunc(v1, vh.y);
                vh.z = bf16_rne(v2); vl.z = lo_trunc(v2, vh.z);
                vh.w = bf16_rne(v3); vl.w = lo_trunc(v3, vh.w);
                const int o = hsw(16 * ni + l16, 32 * wave + 16 * mi + 4 * q);
                *(ushort4*)&h1p[0][0][o] = vh;
                *(ushort4*)&h1p[0][1][o] = vl;
            }
    }

    // ================= main pipeline: ONE barrier per interval ===================
    for (int t = 0; t <= TILES + 1; ++t) {
        __syncthreads();

        // ---- store(t-2): red[t&1] -> global (parity (t-2)&1 == t&1) ----
        if (t >= 2 && tid < TROWS) {
            float4 rv = *(const float4*)&red[t & 1][tid][0];
            out[((rb * TILES + (t - 2)) * TROWS + tid) * RR + r] =
                rv.x + rv.y + rv.z + rv.w;
        }

        // ---- issue long-latency global loads first ----
        float gx[4];
        const bool dg = (t + 2 < TILES);
        if (dg) {
            const int base = (row0g + (t + 2) * TROWS + grow) * DD;
#pragma unroll
            for (int u = 0; u < 4; ++u)
                gx[u] = inputs[base + idx_s[4 * gg + u]] * v_s[4 * gg + u];
        }
        float ex[4];                       // epilogue x's for tile t-1 (L2-warm)
        const int j0 = 8 * wave + 2 * q;
        const bool de = (t >= 1 && t <= TILES);
        if (de) {
            const int baseE = (row0g + (t - 1) * TROWS) * DD;
#pragma unroll
            for (int ni = 0; ni < 2; ++ni)
#pragma unroll
                for (int jj = 0; jj < 2; ++jj)
                    ex[2 * ni + jj] =
                        inputs[(baseE + (16 * ni + l16) * DD) + idx_s[j0 + jj]] *
                        v_s[j0 + jj];
        }

        // ---- P2(t): h2[t&1] = relu(W2^T @ h1[t&1]) ----
        if (t < TILES) {
            const u16* h1h = h1p[t & 1][0];
            const u16* h1l = h1p[t & 1][1];
            u16* const h2h = h2p[t & 1][0];
            u16* const h2l = h2p[t & 1][1];
            f32x4_t acc[2][2] = {{zero4, zero4}, {zero4, zero4}};
#pragma unroll
            for (int ks = 0; ks < 4; ++ks) {
#pragma unroll
                for (int ni = 0; ni < 2; ++ni) {
                    const int o = hsw(16 * ni + l16, ks * 32 + q * 8);
                    bf16x8_t bh = *(const bf16x8_t*)&h1h[o];
                    bf16x8_t bl = *(const bf16x8_t*)&h1l[o];
#pragma unroll
                    for (int mi = 0; mi < 2; ++mi) {
                        f32x4_t a = acc[mi][ni];
                        a = mfma16(a2h[mi][ks], bh, a);
                        a = mfma16(a2l[mi][ks], bh, a);
                        a = mfma16(a2h[mi][ks], bl, a);
                        acc[mi][ni] = a;
                    }
                }
            }
#pragma unroll
            for (int mi = 0; mi < 2; ++mi)
#pragma unroll
                for (int ni = 0; ni < 2; ++ni) {
                    ushort4 vh, vl;
                    float v0 = fmaxf(acc[mi][ni][0], 0.f), v1 = fmaxf(acc[mi][ni][1], 0.f);
                    float v2 = fmaxf(acc[mi][ni][2], 0.f), v3 = fmaxf(acc[mi][ni][3], 0.f);
                    vh.x = bf16_rne(v0); vl.x = lo_trunc(v0, vh.x);
                    vh.y = bf16_rne(v1); vl.y = lo_trunc(v1, vh.y);
                    vh.z = bf16_rne(v2); vl.z = lo_trunc(v2, vh.z);
                    vh.w = bf16_rne(v3); vl.w = lo_trunc(v3, vh.w);
                    const int o = hsw(16 * ni + l16, 32 * wave + 16 * mi + 4 * q);
                    *(ushort4*)&h2h[o] = vh;
                    *(ushort4*)&h2l[o] = vl;
                }
        }

        // ---- P1(t+1): h1[(t+1)&1] = relu(W1^T @ xg[(t+1)&1]) ----
        if (t + 1 < TILES) {
            const int b = (t + 1) & 1;
            bf16x8_t bh[2], bl[2];
#pragma unroll
            for (int ni = 0; ni < 2; ++ni) {
                const int o = xsw(16 * ni + l16, q * 8);
                bh[ni] = *(const bf16x8_t*)&xgp[b][0][o];
                bl[ni] = *(const bf16x8_t*)&xgp[b][1][o];
            }
#pragma unroll
            for (int mi = 0; mi < 2; ++mi)
#pragma unroll
                for (int ni = 0; ni < 2; ++ni) {
                    f32x4_t a = zero4;
                    a = mfma16(a1h[mi], bh[ni], a);
                    a = mfma16(a1l[mi], bh[ni], a);
                    a = mfma16(a1h[mi], bl[ni], a);
                    ushort4 vh, vl;
                    float v0 = fmaxf(a[0], 0.f), v1 = fmaxf(a[1], 0.f);
                    float v2 = fmaxf(a[2], 0.f), v3 = fmaxf(a[3], 0.f);
                    vh.x = bf16_rne(v0); vl.x = lo_trunc(v0, vh.x);
                    vh.y = bf16_rne(v1); vl.y = lo_trunc(v1, vh.y);
                    vh.z = bf16_rne(v2); vl.z = lo_trunc(v2, vh.z);
                    vh.w = bf16_rne(v3); vl.w = lo_trunc(v3, vh.w);
                    const int o = hsw(16 * ni + l16, 32 * wave + 16 * mi + 4 * q);
                    *(ushort4*)&h1p[b][0][o] = vh;
                    *(ushort4*)&h1p[b][1][o] = vl;
                }
        }

        // ---- gather-store(t+2) -> xg[t&1] ----
        if (dg) {
            ushort4 gh, gl;
            gh.x = bf16_rne(gx[0]); gl.x = lo_trunc(gx[0], gh.x);
            gh.y = bf16_rne(gx[1]); gl.y = lo_trunc(gx[1], gh.y);
            gh.z = bf16_rne(gx[2]); gl.z = lo_trunc(gx[2], gh.z);
            gh.w = bf16_rne(gx[3]); gl.w = lo_trunc(gx[3], gh.w);
            const int o = xsw(grow, 4 * gg);
            *(ushort4*)&xgp[t & 1][0][o] = gh;
            *(ushort4*)&xgp[t & 1][1][o] = gl;
        }

        // ---- P3(t-1) + epilogue(t-1): reads h2[(t-1)&1] ----
        if (de) {
            const int tm = t - 1;
            const u16* h2h = h2p[tm & 1][0];
            const u16* h2l = h2p[tm & 1][1];
            f32x4_t acc3[2] = {zero4, zero4};
#pragma unroll
            for (int ks = 0; ks < 4; ++ks) {
#pragma unroll
                for (int ni = 0; ni < 2; ++ni) {
                    const int o = hsw(16 * ni + l16, ks * 32 + q * 8);
                    bf16x8_t bh = *(const bf16x8_t*)&h2h[o];
                    bf16x8_t bl = *(const bf16x8_t*)&h2l[o];
                    f32x4_t a = acc3[ni];
                    a = mfma16(aoh[ks], bh, a);
                    a = mfma16(aol[ks], bh, a);
                    a = mfma16(aoh[ks], bl, a);
                    acc3[ni] = a;
                }
            }
            // epilogue: acc3[ni] = out^T[16w+4q+i][16ni+l16]; i even=shift, odd=log_s
            const float vj0 = v_s[j0], vj1 = v_s[j0 + 1];
            float p[2];
#pragma unroll
            for (int ni = 0; ni < 2; ++ni) {
                const float u0 = (ex[2 * ni + 0] - acc3[ni][0]) * __expf(-acc3[ni][1]);
                const float u1 = (ex[2 * ni + 1] - acc3[ni][2]) * __expf(-acc3[ni][3]);
                p[ni] = (-0.5f * u0 * u0 - 0.91893853320467266954f - acc3[ni][1]) * vj0
                      + (-0.5f * u1 * u1 - 0.91893853320467266954f - acc3[ni][3]) * vj1;
            }
#pragma unroll
            for (int ni = 0; ni < 2; ++ni) {
                p[ni] += __shfl_xor(p[ni], 16, 64);
                p[ni] += __shfl_xor(p[ni], 32, 64);
            }
            if (q == 0) {
#pragma unroll
                for (int ni = 0; ni < 2; ++ni)
                    red[tm & 1][16 * ni + l16][wave] = p[ni];
            }
        }
    }
}

extern "C" void kernel_launch(void* const* d_in, const int* in_sizes, int n_in,
                              void* d_out, int out_size, void* d_ws, size_t ws_size,
                              hipStream_t stream)
{
    const float* inputs = (const float*)d_in[0];
    const float* W1     = (const float*)d_in[1];
    const float* W2     = (const float*)d_in[2];
    const float* Wout   = (const float*)d_in[3];
    const int*   idx    = (const int*)d_in[4];
    const int*   valid  = (const int*)d_in[5];
    const int*   M1     = (const int*)d_in[6];
    const int*   M2     = (const int*)d_in[7];
    const int*   Mout   = (const int*)d_in[8];
    float*       out    = (float*)d_out;

    hipLaunchKernelGGL(made_flow_r10, dim3(RR * BPR), dim3(256), 0, stream,
                       inputs, W1, W2, Wout, idx, valid, M1, M2, Mout, out);
}